// Round 10
// baseline (96.728 us; speedup 1.0000x reference)
//
#include <hip/hip_runtime.h>
#include <stdint.h>

#define BB 512
#define TT 500
#define KK 64
#define DD 64
#define NROWS (BB*TT)
#define EVS 512          // padded ev row stride (bytes)

// ---------------- kernel A: stream chain -> event bytes; params once ----------------
// ev[b*EVS + t] = k | (y<<6). chain dtype (bf16 vs f32) sniffed per-wave from
// its first 256 B: f32 one-hot row = 64 words w/ exactly 1 nonzero; bf16 = 2.
__launch_bounds__(256, 8)
__global__ void ev_stream(const uint32_t* __restrict__ chainw,
                          const int* __restrict__ corr,
                          const float* __restrict__ embd,
                          const float* __restrict__ Wf,
                          const float* __restrict__ bias,
                          uint8_t* __restrict__ ev,
                          float4* __restrict__ params4,
                          float* __restrict__ p1i) {
    // ---- per-k parameters, computed once by block 0 / lanes 0..63 ----
    if (blockIdx.x == 0 && threadIdx.x < KK) {
        const int k = threadIdx.x;
        float l0 = bias[0], l1 = bias[1], l2 = bias[2], l3 = bias[3], l4 = bias[4];
        const float4* er = (const float4*)(embd + k * DD);
        const float4* w0 = (const float4*)(Wf + 0 * DD);
        const float4* w1 = (const float4*)(Wf + 1 * DD);
        const float4* w2 = (const float4*)(Wf + 2 * DD);
        const float4* w3 = (const float4*)(Wf + 3 * DD);
        const float4* w4 = (const float4*)(Wf + 4 * DD);
#pragma unroll 4
        for (int d4 = 0; d4 < DD / 4; ++d4) {
            float4 e = er[d4];
            float4 a;
            a = w0[d4]; l0 = fmaf(e.x,a.x,fmaf(e.y,a.y,fmaf(e.z,a.z,fmaf(e.w,a.w,l0))));
            a = w1[d4]; l1 = fmaf(e.x,a.x,fmaf(e.y,a.y,fmaf(e.z,a.z,fmaf(e.w,a.w,l1))));
            a = w2[d4]; l2 = fmaf(e.x,a.x,fmaf(e.y,a.y,fmaf(e.z,a.z,fmaf(e.w,a.w,l2))));
            a = w3[d4]; l3 = fmaf(e.x,a.x,fmaf(e.y,a.y,fmaf(e.z,a.z,fmaf(e.w,a.w,l3))));
            a = w4[d4]; l4 = fmaf(e.x,a.x,fmaf(e.y,a.y,fmaf(e.z,a.z,fmaf(e.w,a.w,l4))));
        }
        auto sig = [](float x) { return 1.0f / (1.0f + __expf(-x)); };
        params4[k] = make_float4(sig(2.f*l2),    // g0 = p(y=1|s=0)
                                 sig(-2.f*l3),   // g1 = p(y=1|s=1)
                                 sig(2.f*l0),    // t10 = p(s'=1|s=0)
                                 sig(-2.f*l1));  // t11 = p(s'=1|s=1)
        p1i[k] = sig(2.f*l4);                    // initial p(s=1)
    }

    // ---- dtype sniff ----
    const int lane = threadIdx.x & 63;
    uint32_t sv = chainw[lane];
    unsigned long long sm = __ballot(sv != 0u);
    const bool isb = (__popcll(sm) >= 2);

    const int gid = blockIdx.x * blockDim.x + threadIdx.x;
    const int gsz = gridDim.x * blockDim.x;
    const uint4* cb = (const uint4*)chainw;

    if (isb) {
        const int N4 = NROWS * 8;                  // 128 B rows: 8 uint4 each
        for (int f = gid; f < N4; f += gsz) {
            uint4 v = cb[f];
            uint32_t wd[4] = {v.x, v.y, v.z, v.w};
            int j = -1;
#pragma unroll
            for (int q = 0; q < 4; ++q) {
                if ((wd[q] & 0xFFFFu) == 0x3F80u) j = q * 2;
                if ((wd[q] >> 16)     == 0x3F80u) j = q * 2 + 1;
            }
            if (j >= 0) {
                int row = f >> 3;
                int b = row / TT;                  // magic-mul div
                int t = row - b * TT;
                int y = corr[row] & 1;
                ev[b * EVS + t] = (uint8_t)(((f & 7) * 8 + j) | (y << 6));
            }
        }
    } else {
        const int N4 = NROWS * 16;                 // 256 B rows: 16 uint4 each
        for (int f = gid; f < N4; f += gsz) {
            uint4 v = cb[f];
            int j = (v.x == 0x3F800000u) ? 0 : (v.y == 0x3F800000u) ? 1
                  : (v.z == 0x3F800000u) ? 2 : (v.w == 0x3F800000u) ? 3 : -1;
            if (j >= 0) {
                int row = f >> 4;
                int b = row / TT;
                int t = row - b * TT;
                int y = corr[row] & 1;
                ev[b * EVS + t] = (uint8_t)(((f & 15) * 4 + j) | (y << 6));
            }
        }
    }
}

// ---------------- kernel B: one wave per b, branchless lockstep walk ----------------
// lane = k. Per t: broadcast event byte; the single matching lane emits
// log-probs and updates its scalar state. No sort, no multi-wave barriers.
__launch_bounds__(64, 8)
__global__ void bkt_walk(const uint8_t* __restrict__ ev,
                         const float4* __restrict__ params4,
                         const float* __restrict__ p1i,
                         float2* __restrict__ out) {
    __shared__ uint64_t evs8[EVS / 8];             // 512 B
    __shared__ __align__(16) float out_s[TT][2];

    const int b = blockIdx.x;
    const int lane = threadIdx.x;

    const float4 P = params4[lane];
    const float g0 = P.x, g1 = P.y, t10 = P.z, t11 = P.w;
    const float dg = g1 - g0, dt = t11 - t10, g1c = 1.f - g1;
    float p1 = p1i[lane];

    evs8[lane] = ((const uint64_t*)(ev + (size_t)b * EVS))[lane];
    __syncthreads();

    int t = 0;
    for (int c8 = 0; c8 < TT / 8 + 1; ++c8) {      // 62 full chunks + 4-tail
        uint64_t u = evs8[c8];                     // broadcast read
        const int n = (c8 < TT / 8) ? 8 : (TT - (TT / 8) * 8);
#pragma unroll 8
        for (int j = 0; j < 8; ++j) {
            if (j < n) {
                uint32_t e = (uint32_t)(u >> (8 * j)) & 0xFFu;
                float pe1 = fmaf(p1, dg, g0);
                float pe0 = 1.f - pe1;
                if ((e & 63u) == (uint32_t)lane) {
                    out_s[t + j][0] = __logf(pe0);
                    out_s[t + j][1] = __logf(pe1);
                    float gy  = (e >> 6) ? g1  : g1c;
                    float pyy = (e >> 6) ? pe1 : pe0;
                    float w1 = p1 * __fdividef(gy, pyy);
                    p1 = fmaf(w1, dt, t10);
                }
            }
        }
        t += 8;
    }
    __syncthreads();

    // coalesced store: 500 float2 = 4000 B = 250 uint4
    uint4* dst = (uint4*)(out + (size_t)b * TT);
    const uint4* src = (const uint4*)out_s;
    for (int i = lane; i < 250; i += 64) dst[i] = src[i];
}

extern "C" void kernel_launch(void* const* d_in, const int* in_sizes, int n_in,
                              void* d_out, int out_size, void* d_ws, size_t ws_size,
                              hipStream_t stream) {
    // Identify inputs by flat element count (robust to ordering).
    const void* p_corr = nullptr, *p_chain = nullptr, *p_embd = nullptr,
              * p_Wf = nullptr, *p_bias = nullptr;
    for (int i = 0; i < n_in; ++i) {
        switch (in_sizes[i]) {
            case BB * TT:        p_corr  = d_in[i]; break;   // 256000
            case BB * TT * KK:   p_chain = d_in[i]; break;   // 16384000
            case KK * DD:        p_embd  = d_in[i]; break;   // 4096
            case 5 * DD:         p_Wf    = d_in[i]; break;   // 320
            case 5:              p_bias  = d_in[i]; break;
            default: break;
        }
    }
    if (!p_corr)  p_corr  = d_in[0];
    if (!p_chain) p_chain = d_in[1];
    if (!p_embd)  p_embd  = d_in[2];
    if (!p_Wf)    p_Wf    = d_in[3];
    if (!p_bias)  p_bias  = d_in[4];
    (void)out_size;

    // workspace: ev (512*512 = 256 KB) | params4 (1 KB) | p1i (256 B)
    uint8_t* ev      = (uint8_t*)d_ws;
    float4*  params4 = (float4*)((char*)d_ws + BB * EVS);
    float*   p1i     = (float*)((char*)d_ws + BB * EVS + KK * 16);

    ev_stream<<<2048, 256, 0, stream>>>((const uint32_t*)p_chain,
                                        (const int*)p_corr,
                                        (const float*)p_embd,
                                        (const float*)p_Wf,
                                        (const float*)p_bias,
                                        ev, params4, p1i);
    bkt_walk<<<BB, 64, 0, stream>>>(ev, params4, p1i, (float2*)d_out);
}

// Round 11
// 40.531 us; speedup vs baseline: 2.3865x; 2.3865x over previous
//
#include <hip/hip_runtime.h>
#include <stdint.h>

#define BB 512
#define TT 500
#define KK 64
#define DD 64
#define NROWS (BB*TT)

// Workspace layout:
//   bm[cell][16] u64 : words 0-7 = t-bitmap, 8-15 = y-bitmap. cell = b*64+k.
//   4 MiB total, zeroed each call via hipMemsetAsync.
//   params4 / p1i after the bitmaps.

// ---------------- kernel A: stream chain -> per-cell bitmaps; params once ----------------
__launch_bounds__(256, 8)
__global__ void ev_stream(const uint32_t* __restrict__ chainw,
                          const int* __restrict__ corr,
                          const float* __restrict__ embd,
                          const float* __restrict__ Wf,
                          const float* __restrict__ bias,
                          unsigned long long* __restrict__ bm,
                          float4* __restrict__ params4,
                          float* __restrict__ p1i) {
    // ---- per-k parameters, block 0 lanes 0..63 ----
    if (blockIdx.x == 0 && threadIdx.x < KK) {
        const int k = threadIdx.x;
        float l0 = bias[0], l1 = bias[1], l2 = bias[2], l3 = bias[3], l4 = bias[4];
        const float4* er = (const float4*)(embd + k * DD);
        const float4* w0 = (const float4*)(Wf + 0 * DD);
        const float4* w1 = (const float4*)(Wf + 1 * DD);
        const float4* w2 = (const float4*)(Wf + 2 * DD);
        const float4* w3 = (const float4*)(Wf + 3 * DD);
        const float4* w4 = (const float4*)(Wf + 4 * DD);
#pragma unroll 4
        for (int d4 = 0; d4 < DD / 4; ++d4) {
            float4 e = er[d4];
            float4 a;
            a = w0[d4]; l0 = fmaf(e.x,a.x,fmaf(e.y,a.y,fmaf(e.z,a.z,fmaf(e.w,a.w,l0))));
            a = w1[d4]; l1 = fmaf(e.x,a.x,fmaf(e.y,a.y,fmaf(e.z,a.z,fmaf(e.w,a.w,l1))));
            a = w2[d4]; l2 = fmaf(e.x,a.x,fmaf(e.y,a.y,fmaf(e.z,a.z,fmaf(e.w,a.w,l2))));
            a = w3[d4]; l3 = fmaf(e.x,a.x,fmaf(e.y,a.y,fmaf(e.z,a.z,fmaf(e.w,a.w,l3))));
            a = w4[d4]; l4 = fmaf(e.x,a.x,fmaf(e.y,a.y,fmaf(e.z,a.z,fmaf(e.w,a.w,l4))));
        }
        auto sig = [](float x) { return 1.0f / (1.0f + __expf(-x)); };
        params4[k] = make_float4(sig(2.f*l2),    // g0 = p(y=1|s=0)
                                 sig(-2.f*l3),   // g1 = p(y=1|s=1)
                                 sig(2.f*l0),    // t10 = p(s'=1|s=0)
                                 sig(-2.f*l1));  // t11 = p(s'=1|s=1)
        p1i[k] = sig(2.f*l4);                    // initial p(s=1)
    }

    // ---- dtype sniff: f32 one-hot row 0 = 1 nonzero word in first 64; bf16 = 2 ----
    const int lane = threadIdx.x & 63;
    uint32_t sv = chainw[lane];
    unsigned long long sm = __ballot(sv != 0u);
    const bool isb = (__popcll(sm) >= 2);

    const int wid = (blockIdx.x * blockDim.x + threadIdx.x) >> 6;   // 0..8191
    const uint4* cb = (const uint4*)chainw;

    auto emit = [&](int row, int k) {
        int b = row / TT;                         // magic-mul (constant divisor)
        int t = row - b * TT;
        int y = corr[row] & 1;
        unsigned long long* c = bm + ((size_t)(b * KK + k) << 4);
        unsigned long long bit = 1ull << (t & 63);
        atomicOr(&c[t >> 6], bit);
        if (y) atomicOr(&c[8 + (t >> 6)], bit);
    };

    if (isb) {
        // bf16: row = 128 B = 8 uint4. 4 KiB wave chunks: 8000 waves exactly.
        const int base = wid * 256;
        if (base >= NROWS * 8) return;
        uint4 r[4];
#pragma unroll
        for (int q = 0; q < 4; ++q) r[q] = cb[base + lane + q * 64];
#pragma unroll
        for (int q = 0; q < 4; ++q) {
            uint4 v = r[q];
            if ((v.x | v.y | v.z | v.w) == 0u) continue;
            int f = base + lane + q * 64;
            int wi = v.x ? 0 : (v.y ? 1 : (v.z ? 2 : 3));
            uint32_t nw = v.x ? v.x : (v.y ? v.y : (v.z ? v.z : v.w));
            int j = wi * 2 + ((nw >> 16) ? 1 : 0);
            emit(f >> 3, (f & 7) * 8 + j);
        }
    } else {
        // f32: row = 256 B = 16 uint4. 8 KiB wave chunks: 8000 waves exactly.
        const int base = wid * 512;
        if (base >= NROWS * 16) return;
        uint4 r[8];
#pragma unroll
        for (int q = 0; q < 8; ++q) r[q] = cb[base + lane + q * 64];
#pragma unroll
        for (int q = 0; q < 8; ++q) {
            uint4 v = r[q];
            if ((v.x | v.y | v.z | v.w) == 0u) continue;
            int f = base + lane + q * 64;
            int wi = v.x ? 0 : (v.y ? 1 : (v.z ? 2 : 3));
            emit(f >> 4, (f & 15) * 4 + wi);
        }
    }
}

// ---------------- kernel B: thread = (b,k) cell; walk bitmap bits in t-order ----------------
__launch_bounds__(64, 8)
__global__ void bkt_bits(const unsigned long long* __restrict__ bm,
                         const float4* __restrict__ params4,
                         const float* __restrict__ p1i,
                         float2* __restrict__ out) {
    const int b = blockIdx.x;
    const int lane = threadIdx.x;                  // = k
    const unsigned long long* c = bm + ((size_t)(b * KK + lane) << 4);

    unsigned long long tm[8], ym[8];
#pragma unroll
    for (int q = 0; q < 8; ++q) tm[q] = c[q];
#pragma unroll
    for (int q = 0; q < 8; ++q) ym[q] = c[8 + q];

    const float4 P = params4[lane];
    const float g0 = P.x, g1 = P.y, t10 = P.z, t11 = P.w;
    const float dg = g1 - g0, dt = t11 - t10, g1c = 1.f - g1;
    float p1 = p1i[lane];

    float2* ob = out + (size_t)b * TT;
#pragma unroll
    for (int q = 0; q < 8; ++q) {
        unsigned long long tb = tm[q];
        const unsigned long long yb = ym[q];
        while (tb) {
            int j = __builtin_ctzll(tb);
            tb &= tb - 1;
            int t = q * 64 + j;
            int y = (int)((yb >> j) & 1ull);
            float pe1 = fmaf(p1, dg, g0);
            float pe0 = 1.f - pe1;
            ob[t] = make_float2(__logf(pe0), __logf(pe1));
            float gy  = y ? g1  : g1c;
            float pyy = y ? pe1 : pe0;
            p1 = fmaf(p1 * __fdividef(gy, pyy), dt, t10);
        }
    }
}

extern "C" void kernel_launch(void* const* d_in, const int* in_sizes, int n_in,
                              void* d_out, int out_size, void* d_ws, size_t ws_size,
                              hipStream_t stream) {
    // Identify inputs by flat element count (robust to ordering).
    const void* p_corr = nullptr, *p_chain = nullptr, *p_embd = nullptr,
              * p_Wf = nullptr, *p_bias = nullptr;
    for (int i = 0; i < n_in; ++i) {
        switch (in_sizes[i]) {
            case BB * TT:        p_corr  = d_in[i]; break;   // 256000
            case BB * TT * KK:   p_chain = d_in[i]; break;   // 16384000
            case KK * DD:        p_embd  = d_in[i]; break;   // 4096
            case 5 * DD:         p_Wf    = d_in[i]; break;   // 320
            case 5:              p_bias  = d_in[i]; break;
            default: break;
        }
    }
    if (!p_corr)  p_corr  = d_in[0];
    if (!p_chain) p_chain = d_in[1];
    if (!p_embd)  p_embd  = d_in[2];
    if (!p_Wf)    p_Wf    = d_in[3];
    if (!p_bias)  p_bias  = d_in[4];
    (void)out_size;

    const size_t BM_BYTES = (size_t)BB * KK * 16 * 8;        // 4 MiB
    unsigned long long* bm = (unsigned long long*)d_ws;
    float4* params4 = (float4*)((char*)d_ws + BM_BYTES);
    float*  p1i     = (float*)((char*)d_ws + BM_BYTES + KK * 16);

    hipMemsetAsync(d_ws, 0, BM_BYTES, stream);

    ev_stream<<<2048, 256, 0, stream>>>((const uint32_t*)p_chain,
                                        (const int*)p_corr,
                                        (const float*)p_embd,
                                        (const float*)p_Wf,
                                        (const float*)p_bias,
                                        bm, params4, p1i);
    bkt_bits<<<BB, 64, 0, stream>>>(bm, params4, p1i, (float2*)d_out);
}

// Round 12
// 25.659 us; speedup vs baseline: 3.7697x; 1.5796x over previous
//
#include <hip/hip_runtime.h>
#include <stdint.h>

#define BB 512
#define TT 500
#define KK 64
#define DD 64
#define WPB 4            // waves per block (kernel A)

typedef unsigned long long ull;

// Workspace: tbm[512][8][64] u64 (2 MiB) | ybm same (2 MiB) | params4 | p1i.
// Every word of tbm/ybm is written unconditionally each call -> no init needed.

// ---------------- kernel A: chain -> per-(b,k) bitmaps; params once ----------------
// Wave = (b, window w): lane l owns row t = w*64+l (one full 128/256 B row).
// LDS slot per wave: tmask[64], ymask[64] built with LDS atomicOr (wave-local,
// in-order, no barriers), then stored coalesced to bm[b][w][*].
__launch_bounds__(256, 4)
__global__ void ev_stream(const uint32_t* __restrict__ chainw,
                          const int* __restrict__ corr,
                          const float* __restrict__ embd,
                          const float* __restrict__ Wf,
                          const float* __restrict__ bias,
                          ull* __restrict__ tbm,
                          ull* __restrict__ ybm,
                          float4* __restrict__ params4,
                          float* __restrict__ p1i) {
    // ---- per-k parameters, block 0 lanes 0..63 ----
    if (blockIdx.x == 0 && threadIdx.x < KK) {
        const int k = threadIdx.x;
        float l0 = bias[0], l1 = bias[1], l2 = bias[2], l3 = bias[3], l4 = bias[4];
        const float4* er = (const float4*)(embd + k * DD);
        const float4* w0 = (const float4*)(Wf + 0 * DD);
        const float4* w1 = (const float4*)(Wf + 1 * DD);
        const float4* w2 = (const float4*)(Wf + 2 * DD);
        const float4* w3 = (const float4*)(Wf + 3 * DD);
        const float4* w4 = (const float4*)(Wf + 4 * DD);
#pragma unroll 4
        for (int d4 = 0; d4 < DD / 4; ++d4) {
            float4 e = er[d4];
            float4 a;
            a = w0[d4]; l0 = fmaf(e.x,a.x,fmaf(e.y,a.y,fmaf(e.z,a.z,fmaf(e.w,a.w,l0))));
            a = w1[d4]; l1 = fmaf(e.x,a.x,fmaf(e.y,a.y,fmaf(e.z,a.z,fmaf(e.w,a.w,l1))));
            a = w2[d4]; l2 = fmaf(e.x,a.x,fmaf(e.y,a.y,fmaf(e.z,a.z,fmaf(e.w,a.w,l2))));
            a = w3[d4]; l3 = fmaf(e.x,a.x,fmaf(e.y,a.y,fmaf(e.z,a.z,fmaf(e.w,a.w,l3))));
            a = w4[d4]; l4 = fmaf(e.x,a.x,fmaf(e.y,a.y,fmaf(e.z,a.z,fmaf(e.w,a.w,l4))));
        }
        auto sig = [](float x) { return 1.0f / (1.0f + __expf(-x)); };
        params4[k] = make_float4(sig(2.f*l2),    // g0 = p(y=1|s=0)
                                 sig(-2.f*l3),   // g1 = p(y=1|s=1)
                                 sig(2.f*l0),    // t10 = p(s'=1|s=0)
                                 sig(-2.f*l1));  // t11 = p(s'=1|s=1)
        p1i[k] = sig(2.f*l4);                    // initial p(s=1)
    }

    // ---- dtype sniff: f32 one-hot row 0 -> 1 nonzero word in first 64; bf16 -> 2 ----
    const int lane = threadIdx.x & 63;
    const int wv = threadIdx.x >> 6;
    uint32_t sv = chainw[lane];
    ull sm = __ballot(sv != 0u);
    const bool isb = (__popcll(sm) >= 2);

    const int wid = blockIdx.x * WPB + wv;       // 0..4095
    const int b = wid >> 3, w = wid & 7;
    const int t = w * 64 + lane;
    const bool live = (t < TT);

    __shared__ ull tmask[WPB][KK];
    __shared__ ull ymask[WPB][KK];
    tmask[wv][lane] = 0;                         // wave-local slot; LDS ops in-order
    ymask[wv][lane] = 0;

    int y = 0;
    if (live) y = corr[b * TT + t] & 1;

    int k = -1;
    if (isb) {                                   // bf16 row = 128 B = 8 uint4
        const uint4* rp = (const uint4*)chainw + (((size_t)b * TT + t) << 3);
        if (live) {
            uint4 r[8];
#pragma unroll
            for (int q = 0; q < 8; ++q) r[q] = rp[q];
#pragma unroll
            for (int q = 0; q < 8; ++q) {
                uint4 v = r[q];
                if ((v.x | v.y | v.z | v.w) != 0u) {
                    int widx; uint32_t nw;
                    if (v.x)      { widx = 0; nw = v.x; }
                    else if (v.y) { widx = 1; nw = v.y; }
                    else if (v.z) { widx = 2; nw = v.z; }
                    else          { widx = 3; nw = v.w; }
                    k = q * 8 + widx * 2 + ((nw >> 16) ? 1 : 0);
                }
            }
        }
    } else {                                     // f32 row = 256 B = 16 uint4
        const uint4* rp = (const uint4*)chainw + (((size_t)b * TT + t) << 4);
        if (live) {
            uint4 r[16];
#pragma unroll
            for (int q = 0; q < 16; ++q) r[q] = rp[q];
#pragma unroll
            for (int q = 0; q < 16; ++q) {
                uint4 v = r[q];
                if ((v.x | v.y | v.z | v.w) != 0u) {
                    int widx;
                    if (v.x)      widx = 0;
                    else if (v.y) widx = 1;
                    else if (v.z) widx = 2;
                    else          widx = 3;
                    k = q * 4 + widx;
                }
            }
        }
    }

    if (k >= 0) {
        atomicOr(&tmask[wv][k], 1ull << lane);
        if (y) atomicOr(&ymask[wv][k], 1ull << lane);
    }

    // unconditional coalesced store of this wave's 64+64 words
    const size_t o = (((size_t)b * 8 + w) << 6) + lane;
    tbm[o] = tmask[wv][lane];
    ybm[o] = ymask[wv][lane];
}

// ---------------- kernel B: thread = (b,k); ctz-walk bitmap, scalar filter ----------------
__launch_bounds__(128, 8)
__global__ void bkt_bits(const ull* __restrict__ tbm,
                         const ull* __restrict__ ybm,
                         const float4* __restrict__ params4,
                         const float* __restrict__ p1i,
                         float2* __restrict__ out) {
    const int lane = threadIdx.x & 63;           // = k
    const int b = blockIdx.x * 2 + (threadIdx.x >> 6);

    const ull* tp = tbm + ((size_t)b << 9) + lane;   // [b][w][k], w stride 64
    const ull* yp = ybm + ((size_t)b << 9) + lane;
    ull tm[8], ym[8];
#pragma unroll
    for (int w = 0; w < 8; ++w) tm[w] = tp[(size_t)w << 6];
#pragma unroll
    for (int w = 0; w < 8; ++w) ym[w] = yp[(size_t)w << 6];

    const float4 P = params4[lane];
    const float g0 = P.x, g1 = P.y, t10 = P.z, t11 = P.w;
    const float dg = g1 - g0, dt = t11 - t10, g1c = 1.f - g1;
    float p1 = p1i[lane];

    float2* ob = out + (size_t)b * TT;
#pragma unroll
    for (int w = 0; w < 8; ++w) {
        ull tb = tm[w];
        const ull yb = ym[w];
        while (tb) {
            int j = __builtin_ctzll(tb);
            tb &= tb - 1;
            int t = w * 64 + j;
            int y = (int)((yb >> j) & 1ull);
            float pe1 = fmaf(p1, dg, g0);
            float pe0 = 1.f - pe1;
            ob[t] = make_float2(__logf(pe0), __logf(pe1));
            float gy  = y ? g1  : g1c;
            float pyy = y ? pe1 : pe0;
            p1 = fmaf(p1 * __fdividef(gy, pyy), dt, t10);
        }
    }
}

extern "C" void kernel_launch(void* const* d_in, const int* in_sizes, int n_in,
                              void* d_out, int out_size, void* d_ws, size_t ws_size,
                              hipStream_t stream) {
    // Identify inputs by flat element count (robust to ordering).
    const void* p_corr = nullptr, *p_chain = nullptr, *p_embd = nullptr,
              * p_Wf = nullptr, *p_bias = nullptr;
    for (int i = 0; i < n_in; ++i) {
        switch (in_sizes[i]) {
            case BB * TT:        p_corr  = d_in[i]; break;   // 256000
            case BB * TT * KK:   p_chain = d_in[i]; break;   // 16384000
            case KK * DD:        p_embd  = d_in[i]; break;   // 4096
            case 5 * DD:         p_Wf    = d_in[i]; break;   // 320
            case 5:              p_bias  = d_in[i]; break;
            default: break;
        }
    }
    if (!p_corr)  p_corr  = d_in[0];
    if (!p_chain) p_chain = d_in[1];
    if (!p_embd)  p_embd  = d_in[2];
    if (!p_Wf)    p_Wf    = d_in[3];
    if (!p_bias)  p_bias  = d_in[4];
    (void)out_size;

    const size_t PLANE = (size_t)BB * 8 * KK * 8;            // 2 MiB per plane
    ull*    tbm     = (ull*)d_ws;
    ull*    ybm     = (ull*)((char*)d_ws + PLANE);
    float4* params4 = (float4*)((char*)d_ws + 2 * PLANE);
    float*  p1i     = (float*)((char*)d_ws + 2 * PLANE + KK * 16);

    ev_stream<<<BB * 8 / WPB, 64 * WPB, 0, stream>>>(
        (const uint32_t*)p_chain, (const int*)p_corr,
        (const float*)p_embd, (const float*)p_Wf, (const float*)p_bias,
        tbm, ybm, params4, p1i);
    bkt_bits<<<BB / 2, 128, 0, stream>>>(tbm, ybm, params4, p1i, (float2*)d_out);
}

// Round 13
// 22.539 us; speedup vs baseline: 4.2915x; 1.1384x over previous
//
#include <hip/hip_runtime.h>
#include <stdint.h>

#define BB 512
#define TT 500
#define KK 64
#define DD 64

typedef unsigned long long ull;

// One 512-thread block per batch element b. Zero global scratch.
// Wave w (=t-window) lane l owns row t = w*64+l: finds its one-hot k and
// LDS-atomicOr's bit l into (tmask[w][k], ymask[w][k]). Wave 0 also computes
// the 64 per-k sigmoid params (redundant per block, L2-hot). One barrier;
// then wave 0 lane k ctz-walks its ~8 events and writes float2 log-probs.
__launch_bounds__(512, 4)
__global__ void bkt_fused(const uint32_t* __restrict__ chainw,
                          const int* __restrict__ corr,
                          const float* __restrict__ embd,
                          const float* __restrict__ Wf,
                          const float* __restrict__ bias,
                          float2* __restrict__ out) {
    __shared__ ull tmask[8][KK];
    __shared__ ull ymask[8][KK];

    const int b = blockIdx.x;
    const int tid = threadIdx.x;
    const int wv = tid >> 6, lane = tid & 63;

    // ---- dtype sniff: f32 one-hot row 0 -> 1 nonzero word in first 64; bf16 -> 2 ----
    uint32_t sv = chainw[lane];
    ull sm = __ballot(sv != 0u);
    const bool isb = (__popcll(sm) >= 2);

    // ---- zero this wave's LDS slice (wave-synchronous; no barrier needed) ----
    tmask[wv][lane] = 0;
    ymask[wv][lane] = 0;

    const int t = wv * 64 + lane;
    const bool live = (t < TT);

    int y = 0;
    if (live) y = corr[b * TT + t] & 1;

    // ---- find one-hot k in this row (independent vector loads) ----
    int k = -1;
    if (isb) {                                   // bf16 row = 128 B = 8 uint4
        const uint4* rp = (const uint4*)chainw + (((size_t)b * TT + t) << 3);
        if (live) {
            uint4 r[8];
#pragma unroll
            for (int q = 0; q < 8; ++q) r[q] = rp[q];
#pragma unroll
            for (int q = 0; q < 8; ++q) {
                uint4 v = r[q];
                if ((v.x | v.y | v.z | v.w) != 0u) {
                    int widx; uint32_t nw;
                    if (v.x)      { widx = 0; nw = v.x; }
                    else if (v.y) { widx = 1; nw = v.y; }
                    else if (v.z) { widx = 2; nw = v.z; }
                    else          { widx = 3; nw = v.w; }
                    k = q * 8 + widx * 2 + ((nw >> 16) ? 1 : 0);
                }
            }
        }
    } else {                                     // f32 row = 256 B = 16 uint4
        const uint4* rp = (const uint4*)chainw + (((size_t)b * TT + t) << 4);
        if (live) {
            uint4 r[16];
#pragma unroll
            for (int q = 0; q < 16; ++q) r[q] = rp[q];
#pragma unroll
            for (int q = 0; q < 16; ++q) {
                uint4 v = r[q];
                if ((v.x | v.y | v.z | v.w) != 0u) {
                    int widx;
                    if (v.x)      widx = 0;
                    else if (v.y) widx = 1;
                    else if (v.z) widx = 2;
                    else          widx = 3;
                    k = q * 4 + widx;
                }
            }
        }
    }

    // ---- per-k params (wave 0 only; overlaps other waves' loads) ----
    float g0, g1, t10, t11, p1;
    if (wv == 0) {
        float l0 = bias[0], l1 = bias[1], l2 = bias[2], l3 = bias[3], l4 = bias[4];
        const float4* er = (const float4*)(embd + lane * DD);
        const float4* w0 = (const float4*)(Wf + 0 * DD);
        const float4* w1 = (const float4*)(Wf + 1 * DD);
        const float4* w2 = (const float4*)(Wf + 2 * DD);
        const float4* w3 = (const float4*)(Wf + 3 * DD);
        const float4* w4 = (const float4*)(Wf + 4 * DD);
#pragma unroll 4
        for (int d4 = 0; d4 < DD / 4; ++d4) {
            float4 e = er[d4];
            float4 a;
            a = w0[d4]; l0 = fmaf(e.x,a.x,fmaf(e.y,a.y,fmaf(e.z,a.z,fmaf(e.w,a.w,l0))));
            a = w1[d4]; l1 = fmaf(e.x,a.x,fmaf(e.y,a.y,fmaf(e.z,a.z,fmaf(e.w,a.w,l1))));
            a = w2[d4]; l2 = fmaf(e.x,a.x,fmaf(e.y,a.y,fmaf(e.z,a.z,fmaf(e.w,a.w,l2))));
            a = w3[d4]; l3 = fmaf(e.x,a.x,fmaf(e.y,a.y,fmaf(e.z,a.z,fmaf(e.w,a.w,l3))));
            a = w4[d4]; l4 = fmaf(e.x,a.x,fmaf(e.y,a.y,fmaf(e.z,a.z,fmaf(e.w,a.w,l4))));
        }
        auto sig = [](float x) { return 1.0f / (1.0f + __expf(-x)); };
        t10 = sig( 2.f * l0);    // p(s'=1 | s=0)
        t11 = sig(-2.f * l1);    // p(s'=1 | s=1)
        g0  = sig( 2.f * l2);    // p(y=1 | s=0)
        g1  = sig(-2.f * l3);    // p(y=1 | s=1)
        p1  = sig( 2.f * l4);    // initial p(s=1)
    }

    // ---- deposit event bits (wave-local LDS atomics, in-order) ----
    if (k >= 0) {
        atomicOr(&tmask[wv][k], 1ull << lane);
        if (y) atomicOr(&ymask[wv][k], 1ull << lane);
    }
    __syncthreads();

    // ---- phase 2: wave 0, lane = k ----
    if (wv == 0) {
        const float dg = g1 - g0, dt = t11 - t10, g1c = 1.f - g1;
        float2* ob = out + (size_t)b * TT;
#pragma unroll
        for (int w = 0; w < 8; ++w) {
            ull tb = tmask[w][lane];
            const ull yb = ymask[w][lane];
            while (tb) {
                int j = __builtin_ctzll(tb);
                tb &= tb - 1;
                int tt = w * 64 + j;
                int yy = (int)((yb >> j) & 1ull);
                float pe1 = fmaf(p1, dg, g0);
                float pe0 = 1.f - pe1;
                ob[tt] = make_float2(__logf(pe0), __logf(pe1));
                float gy  = yy ? g1  : g1c;
                float pyy = yy ? pe1 : pe0;
                p1 = fmaf(p1 * __fdividef(gy, pyy), dt, t10);
            }
        }
    }
}

extern "C" void kernel_launch(void* const* d_in, const int* in_sizes, int n_in,
                              void* d_out, int out_size, void* d_ws, size_t ws_size,
                              hipStream_t stream) {
    // Identify inputs by flat element count (robust to ordering).
    const void* p_corr = nullptr, *p_chain = nullptr, *p_embd = nullptr,
              * p_Wf = nullptr, *p_bias = nullptr;
    for (int i = 0; i < n_in; ++i) {
        switch (in_sizes[i]) {
            case BB * TT:        p_corr  = d_in[i]; break;   // 256000
            case BB * TT * KK:   p_chain = d_in[i]; break;   // 16384000
            case KK * DD:        p_embd  = d_in[i]; break;   // 4096
            case 5 * DD:         p_Wf    = d_in[i]; break;   // 320
            case 5:              p_bias  = d_in[i]; break;
            default: break;
        }
    }
    if (!p_corr)  p_corr  = d_in[0];
    if (!p_chain) p_chain = d_in[1];
    if (!p_embd)  p_embd  = d_in[2];
    if (!p_Wf)    p_Wf    = d_in[3];
    if (!p_bias)  p_bias  = d_in[4];
    (void)d_ws; (void)ws_size; (void)out_size;

    bkt_fused<<<BB, 512, 0, stream>>>((const uint32_t*)p_chain,
                                      (const int*)p_corr,
                                      (const float*)p_embd,
                                      (const float*)p_Wf,
                                      (const float*)p_bias,
                                      (float2*)d_out);
}